// Round 17
// baseline (6208.038 us; speedup 1.0000x reference)
//
#include <hip/hip_runtime.h>
#include <hip/hip_bf16.h>

#define V_  32000
#define D_  1024
#define H_  16
#define L_  4
#define T_  1024
#define B_  4
#define HD_ 64
#define FF_ 4096
#define M_  4096
#define QP_ 3072   // fused qkv row pitch

typedef unsigned short u16;
typedef float  f32x4   __attribute__((ext_vector_type(4)));
typedef float  f32x16  __attribute__((ext_vector_type(16)));
typedef __bf16 bf16x8  __attribute__((ext_vector_type(8)));
typedef u16    us8     __attribute__((ext_vector_type(8)));

typedef __attribute__((address_space(1))) void gvoid;
typedef __attribute__((address_space(3))) void lvoid;

__device__ __forceinline__ void glds16(const void* g, void* l) {
  __builtin_amdgcn_global_load_lds((gvoid*)g, (lvoid*)l, 16, 0, 0);
}
__device__ __forceinline__ u16 f2bf(float f) {
  __hip_bfloat16 h = __float2bfloat16(f);
  return reinterpret_cast<u16&>(h);
}

#define BAR() __builtin_amdgcn_s_barrier()
#define VMC(n) asm volatile("s_waitcnt vmcnt(" #n ")" ::: "memory")
#define LGKMC(n) do { asm volatile("s_waitcnt lgkmcnt(" #n ")" ::: "memory"); \
                      __builtin_amdgcn_sched_barrier(0); } while (0)

// ---------------------------------------------------------------- embed ----
__global__ __launch_bounds__(256) void embed_kernel(
    const int* __restrict__ idx, const float* __restrict__ tok,
    const float* __restrict__ pos, float* __restrict__ x)
{
  int bt = blockIdx.x;
  int t  = bt & (T_ - 1);
  int id = idx[bt];
  float4 a = ((const float4*)(tok + (size_t)id * D_))[threadIdx.x];
  float4 p = ((const float4*)(pos + (size_t)t  * D_))[threadIdx.x];
  a.x += p.x; a.y += p.y; a.z += p.z; a.w += p.w;
  ((float4*)(x + (size_t)bt * D_))[threadIdx.x] = a;
}

// ------------------------------------------------------------ layernorm ----
__global__ __launch_bounds__(256) void ln_kernel(
    const float* __restrict__ x, const float* __restrict__ w,
    const float* __restrict__ b, u16* __restrict__ out)
{
  int row = blockIdx.x;
  float4 v = ((const float4*)(x + (size_t)row * D_))[threadIdx.x];
  float s  = v.x + v.y + v.z + v.w;
  float s2 = v.x * v.x + v.y * v.y + v.z * v.z + v.w * v.w;
#pragma unroll
  for (int m = 1; m < 64; m <<= 1) { s += __shfl_xor(s, m); s2 += __shfl_xor(s2, m); }
  __shared__ float ssum[4], ssum2[4];
  int wv = threadIdx.x >> 6;
  if ((threadIdx.x & 63) == 0) { ssum[wv] = s; ssum2[wv] = s2; }
  __syncthreads();
  s  = ssum[0]  + ssum[1]  + ssum[2]  + ssum[3];
  s2 = ssum2[0] + ssum2[1] + ssum2[2] + ssum2[3];
  float mu  = s * (1.f / D_);
  float var = s2 * (1.f / D_) - mu * mu;
  float rs  = rsqrtf(var + 1e-5f);
  float4 wv4 = ((const float4*)w)[threadIdx.x];
  float4 bv4 = ((const float4*)b)[threadIdx.x];
  u16* o = out + (size_t)row * D_ + threadIdx.x * 4;
  o[0] = f2bf((v.x - mu) * rs * wv4.x + bv4.x);
  o[1] = f2bf((v.y - mu) * rs * wv4.y + bv4.y);
  o[2] = f2bf((v.z - mu) * rs * wv4.z + bv4.z);
  o[3] = f2bf((v.w - mu) * rs * wv4.w + bv4.w);
}

// -------------------------------------------- fp32 [R][C] -> bf16 [C][R] ---
__global__ __launch_bounds__(256) void transpose_convert(
    const float* __restrict__ in, u16* __restrict__ out, int R, int C,
    size_t inStride, size_t outStride)
{
  __shared__ float tile[32][33];
  in  += (size_t)blockIdx.z * inStride;
  out += (size_t)blockIdx.z * outStride;
  int c  = blockIdx.x * 32 + threadIdx.x;
  int r0 = blockIdx.y * 32;
#pragma unroll
  for (int j = 0; j < 4; j++)
    tile[threadIdx.y + 8 * j][threadIdx.x] =
        in[(size_t)(r0 + threadIdx.y + 8 * j) * C + c];
  __syncthreads();
  int rr = r0 + threadIdx.x;
  int cb = blockIdx.x * 32;
#pragma unroll
  for (int j = 0; j < 4; j++)
    out[(size_t)(cb + threadIdx.y + 8 * j) * R + rr] =
        f2bf(tile[threadIdx.x][threadIdx.y + 8 * j]);
}

// ------------------------------- V^T materialize: qkv -> vtb[bh][64][T] ----
__global__ __launch_bounds__(256) void vtrans_kernel(
    const u16* __restrict__ qkv, u16* __restrict__ vtb)
{
  __shared__ u16 tile[64][72];
  int tt = blockIdx.x, bh = blockIdx.y;
  int b = bh >> 4, h = bh & 15;
  const u16* src = qkv + ((size_t)(b * T_ + tt * 64)) * QP_ + 2 * D_ + h * HD_;
#pragma unroll
  for (int it = 0; it < 2; it++) {
    int u = it * 256 + threadIdx.x;
    int r = u >> 3, c = (u & 7) << 3;
    *(us8*)&tile[r][c] = *(const us8*)&src[(size_t)r * QP_ + c];
  }
  __syncthreads();
#pragma unroll
  for (int it = 0; it < 2; it++) {
    int u = it * 256 + threadIdx.x;
    int d = u >> 3, t8 = (u & 7) << 3;
    us8 v;
#pragma unroll
    for (int j = 0; j < 8; j++) v[j] = tile[t8 + j][d];
    *(us8*)&vtb[((size_t)bh * HD_ + d) * T_ + tt * 64 + t8] = v;
  }
}

// ---------------------------------------------------- 128x128 GEMM --------
// EPI 0: +bias -> bf16 | 1: +bias,relu -> bf16 | 2: +bias+resid -> f32 | 3: +bias -> f32
template<int EPI>
__global__ __launch_bounds__(256) void gemm_bt(
    const u16* __restrict__ A, const u16* __restrict__ Bt,
    const float* __restrict__ bias, const float* __restrict__ resid,
    void* __restrict__ Cout, int M, int N, int K)
{
  __shared__ u16 As[128 * 32];
  __shared__ u16 Bs[128 * 32];
  const int tid = threadIdx.x;
  const int m0 = blockIdx.x * 128;
  const int n0 = blockIdx.y * 128;
  const int w = tid >> 6, lane = tid & 63, lg = lane >> 4, lr = lane & 15;
  const int wr = w >> 1, wc = w & 1;
  f32x4 acc[4][4] = {};
  const int srow = tid >> 2;
  const int scol = (tid & 3) << 3;
  const u16* ap = A  + (size_t)(m0 + srow) * K + scol;
  const u16* bp = Bt + (size_t)(n0 + srow) * K + scol;
  u16* alds  = &As[tid * 8];
  u16* alds2 = &As[2048 + tid * 8];
  u16* blds  = &Bs[tid * 8];
  u16* blds2 = &Bs[2048 + tid * 8];
  for (int k0 = 0; k0 < K; k0 += 32) {
    __syncthreads();
    glds16(ap + k0,                  alds);
    glds16(ap + (size_t)64 * K + k0, alds2);
    glds16(bp + k0,                  blds);
    glds16(bp + (size_t)64 * K + k0, blds2);
    __syncthreads();
    bf16x8 af[4], bfr[4];
#pragma unroll
    for (int i = 0; i < 4; i++)
      af[i] = *(const bf16x8*)&As[(wr * 64 + i * 16 + lr) * 32 + lg * 8];
#pragma unroll
    for (int j = 0; j < 4; j++)
      bfr[j] = *(const bf16x8*)&Bs[(wc * 64 + j * 16 + lr) * 32 + lg * 8];
#pragma unroll
    for (int i = 0; i < 4; i++)
#pragma unroll
      for (int j = 0; j < 4; j++)
        acc[i][j] = __builtin_amdgcn_mfma_f32_16x16x32_bf16(af[i], bfr[j], acc[i][j], 0, 0, 0);
  }
#pragma unroll
  for (int i = 0; i < 4; i++) {
#pragma unroll
    for (int j = 0; j < 4; j++) {
      int col = n0 + wc * 64 + j * 16 + lr;
      float bv = bias ? bias[col] : 0.f;
#pragma unroll
      for (int r = 0; r < 4; r++) {
        int row = m0 + wr * 64 + i * 16 + lg * 4 + r;
        float val = acc[i][j][r] + bv;
        size_t o = (size_t)row * N + col;
        if (EPI == 0)      ((u16*)Cout)[o]   = f2bf(val);
        else if (EPI == 1) ((u16*)Cout)[o]   = f2bf(val > 0.f ? val : 0.f);
        else if (EPI == 2) ((float*)Cout)[o] = resid[o] + val;
        else               ((float*)Cout)[o] = val;
      }
    }
  }
}

// ---------------------------------------------------- 256x256 GEMM --------
// 32x32x16 MFMA, rotating fragment sets, 1 barrier per K-tile (r7/r10 best).
#define CLUSTER(AF, BV, MS) do { \
  __builtin_amdgcn_s_setprio(1); \
  _Pragma("unroll") for (int mq_ = 0; mq_ < 2; ++mq_) \
  _Pragma("unroll") for (int nq_ = 0; nq_ < 2; ++nq_) \
  _Pragma("unroll") for (int kq_ = 0; kq_ < 2; ++kq_) \
    acc[(MS)+mq_][nq_] = __builtin_amdgcn_mfma_f32_32x32x16_bf16( \
        AF[mq_][kq_], BV[nq_][kq_], acc[(MS)+mq_][nq_], 0, 0, 0); \
  __builtin_amdgcn_s_setprio(0); \
} while (0)

// M fixed = 4096 (16 row-tiles). Grid = 16 * (N/256), flattened 1D.
// EPI 0: +bias -> bf16 | 1: +bias,relu -> bf16
template<int EPI>
__global__ __launch_bounds__(512, 2) void gemm256(
    const u16* __restrict__ A, const u16* __restrict__ Bt,
    const float* __restrict__ bias, void* __restrict__ Cout, int N, int K)
{
  extern __shared__ char smem[];
  const int tid = threadIdx.x;
  // bijective XCD swizzle (m204)
  const int nwg = gridDim.x;
  const int orig = blockIdx.x;
  const int qq = nwg >> 3, rr = nwg & 7, xcd = orig & 7, lid = orig >> 3;
  const int swz = (xcd < rr ? xcd * (qq + 1) : rr * (qq + 1) + (xcd - rr) * qq) + lid;
  const int m0 = (swz & 15) << 8;
  const int n0 = (swz >> 4) << 8;
  const int NT = K >> 6;

  const int wid = tid >> 6, lane = tid & 63;
  const int wr = wid >> 2, wc = wid & 3;
  const int l31 = lane & 31, lh = lane >> 5;
  // parity slot swizzle (verified r6: conflicts 2.46e7 -> 0)
  const int gsw = (lane & 7) ^ ((lane >> 3) & 3);
  const int srow = tid >> 3, sslot = tid & 7;
  const int sg = (srow & 7) ^ ((srow >> 3) & 3);
  const int scol = ((sslot ^ sg) << 3);
  const u16* Ag = A  + (size_t)(m0 + srow) * K + scol;
  const u16* Bg = Bt + (size_t)(n0 + srow) * K + scol;
  char* ldst = smem + tid * 16;

  auto stA = [&](int bb, int kt, int h) {
    const u16* g = Ag + (size_t)(h << 7) * K + (kt << 6);
    char* l = ldst + bb * 65536 + h * 16384;
    glds16(g, l);
    glds16(g + ((size_t)K << 6), l + 8192);
  };
  auto stB = [&](int bb, int kt, int h) {
    const u16* g = Bg + (size_t)(h << 7) * K + (kt << 6);
    char* l = ldst + bb * 65536 + 32768 + h * 16384;
    glds16(g, l);
    glds16(g + ((size_t)K << 6), l + 8192);
  };
  auto ldA = [&](int bb, int mf, int ks) {
    return *(const bf16x8*)(smem + bb * 65536 +
        ((wr * 128 + mf * 32 + l31) << 7) + (((ks * 2 + lh) ^ gsw) << 4));
  };
  auto ldB = [&](int bb, int nf, int ks) {
    return *(const bf16x8*)(smem + bb * 65536 + 32768 +
        ((wc * 64 + nf * 32 + l31) << 7) + (((ks * 2 + lh) ^ gsw) << 4));
  };

  f32x16 acc[4][2] = {};
  bf16x8 afA[2][2], afB[2][2], bfvA[2][2], bfvB[2][2];

  // prologue: stage tile0 fully, drain, barrier
  stA(0, 0, 0); stA(0, 0, 1); stB(0, 0, 0); stB(0, 0, 1);
  VMC(0); BAR();

  for (int t = 0; t < NT; ++t) {
    const int bb = t & 1;
    if (t + 1 < NT) {
      stA(bb ^ 1, t + 1, 0); stA(bb ^ 1, t + 1, 1);
      stB(bb ^ 1, t + 1, 0); stB(bb ^ 1, t + 1, 1);
    }
#pragma unroll
    for (int i = 0; i < 2; i++) {
      afA[i][0]  = ldA(bb, i, 0);     afA[i][1]  = ldA(bb, i, 1);
      bfvA[i][0] = ldB(bb, i, 0);     bfvA[i][1] = ldB(bb, i, 1);
    }
#pragma unroll
    for (int i = 0; i < 2; i++) { afB[i][0] = ldA(bb, 2 + i, 0); afB[i][1] = ldA(bb, 2 + i, 1); }
    LGKMC(4);
    CLUSTER(afA, bfvA, 0);
#pragma unroll
    for (int i = 0; i < 2; i++) { bfvB[i][0] = ldB(bb, i, 2); bfvB[i][1] = ldB(bb, i, 3); }
#pragma unroll
    for (int i = 0; i < 2; i++) { afA[i][0] = ldA(bb, i, 2); afA[i][1] = ldA(bb, i, 3); }
    LGKMC(8);
    CLUSTER(afB, bfvA, 2);
#pragma unroll
    for (int i = 0; i < 2; i++) { afB[i][0] = ldA(bb, 2 + i, 2); afB[i][1] = ldA(bb, 2 + i, 3); }
    LGKMC(4);
    CLUSTER(afA, bfvB, 0);
    LGKMC(0);
    CLUSTER(afB, bfvB, 2);
    VMC(0); BAR();
  }

  // C/D layout (m74/m101): col = lane&31, row = (v&3) + 8*(v>>2) + 4*lh
#pragma unroll
  for (int nf = 0; nf < 2; ++nf) {
    const int col = n0 + wc * 64 + nf * 32 + l31;
    const float bv = bias ? bias[col] : 0.f;
#pragma unroll
    for (int mf = 0; mf < 4; ++mf) {
#pragma unroll
      for (int v = 0; v < 16; ++v) {
        const int row = m0 + wr * 128 + mf * 32 + (v & 3) + 8 * (v >> 2) + 4 * lh;
        float val = acc[mf][nf][v] + bv;
        size_t o = (size_t)row * N + col;
        if (EPI == 0)      ((u16*)Cout)[o]   = f2bf(val);
        else if (EPI == 1) ((u16*)Cout)[o]   = f2bf(val > 0.f ? val : 0.f);
        else               __builtin_nontemporal_store(val, (float*)Cout + o);
      }
    }
  }
}

// ------------------- 512x256 GEMM, 1024 threads, single 96KB buffer -------
// Per-CU delivery cap model (r6-r16: ~10 B/cyc/CU): bigger tile cuts staged
// bytes per output 25% (2*(1/BM+1/BN)). Per-wave structure identical to
// gemm256 (128x64 wave-tile, rotating frags, counted lgkm, parity swizzle).
// EPI 3: +bias -> f32 (nt). M fixed 4096 (8 row-tiles); grid 8*(N/256).
template<int EPI>
__global__ __launch_bounds__(1024, 1) void gemm512(
    const u16* __restrict__ A, const u16* __restrict__ Bt,
    const float* __restrict__ bias, void* __restrict__ Cout, int N, int K)
{
  extern __shared__ char smem[];   // A 64KB + B 32KB
  const int tid = threadIdx.x;
  const int nwg = gridDim.x;
  const int orig = blockIdx.x;
  const int qq = nwg >> 3, rr = nwg & 7, xcd = orig & 7, lid = orig >> 3;
  const int swz = (xcd < rr ? xcd * (qq + 1) : rr * (qq + 1) + (xcd - rr) * qq) + lid;
  const int m0 = (swz & 7) << 9;
  const int n0 = (swz >> 3) << 8;
  const int NT = K >> 6;

  const int wid = tid >> 6, lane = tid & 63;
  const int wr = wid >> 2, wc = wid & 3;      // 4m x 4n waves
  const int l31 = lane & 31, lh = lane >> 5;
  const int gsw = (lane & 7) ^ ((lane >> 3) & 3);
  const int srow = tid >> 3, sslot = tid & 7;     // srow 0..127
  const int sg = (srow & 7) ^ ((srow >> 3) & 3);  // g invariant under +128
  const int scol = ((sslot ^ sg) << 3);
  const u16* Ag = A  + (size_t)(m0 + srow) * K + scol;
  const u16* Bg = Bt + (size_t)(n0 + srow) * K + scol;
  char* ldst = smem + tid * 16;

  auto stage = [&](int kt) {
#pragma unroll
    for (int seg = 0; seg < 4; seg++)          // A rows seg*128 + srow
      glds16(Ag + (size_t)(seg * 128) * K + (kt << 6), ldst + seg * 16384);
#pragma unroll
    for (int seg = 0; seg < 2; seg++)          // B rows seg*128 + srow
      glds16(Bg + (size_t)(seg * 128) * K + (kt << 6), ldst + 65536 + seg * 16384);
  };
  auto ldA = [&](int mf, int ks) {
    return *(const bf16x8*)(smem +
        ((wr * 128 + mf * 32 + l31) << 7) + (((ks * 2 + lh) ^ gsw) << 4));
  };
  auto ldB = [&](int nf, int ks) {
    return *(const bf16x8*)(smem + 65536 +
        ((wc * 64 + nf * 32 + l31) << 7) + (((ks * 2 + lh) ^ gsw) << 4));
  };

  f32x16 acc[4][2] = {};
  bf16x8 afA[2][2], afB[2][2], bfvA[2][2], bfvB[2][2];

  for (int t = 0; t < NT; ++t) {
    BAR();                    // all waves' reads of t-1 retired (LGKMC(0))
    stage(t);
    VMC(0); BAR();            // tile t resident block-wide
#pragma unroll
    for (int i = 0; i < 2; i++) {
      afA[i][0]  = ldA(i, 0);     afA[i][1]  = ldA(i, 1);
      bfvA[i][0] = ldB(i, 0);     bfvA[i][1] = ldB(i, 1);
    }
#pragma unroll
    for (int i = 0; i < 2; i++) { afB[i][0] = ldA(2 + i, 0); afB[i][1] = ldA(2 + i, 1); }
    LGKMC(4);
    CLUSTER(afA, bfvA, 0);
#pragma unroll
    for (int i = 0; i < 2; i++) { bfvB[i][0] = ldB(i, 2); bfvB[i][1] = ldB(i, 3); }
#pragma unroll
    for (int i = 0; i < 2; i++) { afA[i][0] = ldA(i, 2); afA[i][1] = ldA(i, 3); }
    LGKMC(8);
    CLUSTER(afB, bfvA, 2);
#pragma unroll
    for (int i = 0; i < 2; i++) { afB[i][0] = ldA(2 + i, 2); afB[i][1] = ldA(2 + i, 3); }
    LGKMC(4);
    CLUSTER(afA, bfvB, 0);
    LGKMC(0);
    CLUSTER(afB, bfvB, 2);
  }

  // C/D layout: col = lane&31, row = (v&3) + 8*(v>>2) + 4*lh
#pragma unroll
  for (int nf = 0; nf < 2; ++nf) {
    const int col = n0 + wc * 64 + nf * 32 + l31;
    const float bv = bias ? bias[col] : 0.f;
#pragma unroll
    for (int mf = 0; mf < 4; ++mf) {
#pragma unroll
      for (int v = 0; v < 16; ++v) {
        const int row = m0 + wr * 128 + mf * 32 + (v & 3) + 8 * (v >> 2) + 4 * lh;
        float val = acc[mf][nf][v] + bv;
        size_t o = (size_t)row * N + col;
        if (EPI == 3) __builtin_nontemporal_store(val, (float*)Cout + o);
        else          ((float*)Cout)[o] = val;
      }
    }
  }
}

// ---------------------------------------------------- flash attention -----
// reads fused qkv (q,k) + pre-transposed V^T (vtb[bh][64][T]); writes o.
// LPT dispatch: qt reversed so longest blocks issue first.
__global__ __launch_bounds__(512) void attn_kernel(
    const u16* __restrict__ qkv, const u16* __restrict__ vtb,
    u16* __restrict__ o)
{
  __shared__ u16 Ks[2][64][64];
  __shared__ u16 Vs[2][64][64];
  __shared__ u16 Ps[8][16][72];
  const int qt = gridDim.x - 1 - blockIdx.x;
  const int bh = blockIdx.y;
  const int b = bh >> 4, h = bh & 15;
  const int tid = threadIdx.x;
  const int w = tid >> 6, lane = tid & 63, lg = lane >> 4, lr = lane & 15;
  const int q0 = qt * 128;
  const size_t qbase = ((size_t)b * T_) * QP_ + h * HD_;
  const size_t obase = ((size_t)b * T_) * D_ + h * HD_;
  const u16* qb = qkv + qbase;
  const u16* kb = qkv + qbase + D_;
  const u16* vtbh = vtb + (size_t)bh * HD_ * T_;
  bf16x8 qf[2];
  const int qrow = q0 + w * 16 + lr;
#pragma unroll
  for (int ks = 0; ks < 2; ks++)
    qf[ks] = *(const bf16x8*)&qb[(size_t)qrow * QP_ + ks * 32 + lg * 8];
  f32x4 oacc[4] = {};
  float mrun[4] = {-1e30f, -1e30f, -1e30f, -1e30f};
  float lrun[4] = {0.f, 0.f, 0.f, 0.f};
  const int srow = tid >> 3, sslot = tid & 7;
  const int sg = (srow & 7) ^ ((srow >> 3) & 3);
  const int scol = (sslot ^ sg) << 3;
  u16* kdst = &Ks[0][0][0] + tid * 8;
  u16* vdst = &Vs[0][0][0] + tid * 8;
  auto stage = [&](int kt, int bb) {
    glds16(kb + (size_t)(kt * 64 + srow) * QP_ + scol, kdst + bb * 4096);
    glds16(vtbh + (size_t)srow * T_ + kt * 64 + scol, vdst + bb * 4096);
  };
  auto ldK = [&](int bb, int j, int ks) {
    int r = j * 16 + lr;
    int g = (r & 7) ^ ((r >> 3) & 3);
    return *(const bf16x8*)&Ks[bb][r][((ks * 4 + lg) ^ g) << 3];
  };
  auto ldV = [&](int bb, int jd, int ks) {
    int r = jd * 16 + lr;
    int g = (r & 7) ^ ((r >> 3) & 3);
    return *(const bf16x8*)&Vs[bb][r][((ks * 4 + lg) ^ g) << 3];
  };

  const int ktmax = 2 * qt + 1;
  stage(0, 0);
  VMC(0); BAR();
  for (int kt = 0; kt <= ktmax; kt++) {
    const int bb = kt & 1;
    if (kt < ktmax) stage(kt + 1, bb ^ 1);
    f32x4 s[4] = {};
#pragma unroll
    for (int ks = 0; ks < 2; ks++)
#pragma unroll
      for (int j = 0; j < 4; j++)
        s[j] = __builtin_amdgcn_mfma_f32_16x16x32_bf16(qf[ks], ldK(bb, j, ks), s[j], 0, 0, 0);
#pragma unroll
    for (int j = 0; j < 4; j++) {
      int key = kt * 64 + j * 16 + lr;
#pragma unroll
      for (int r = 0; r < 4; r++) {
        int qr = q0 + w * 16 + lg * 4 + r;
        s[j][r] = (key <= qr) ? s[j][r] * 0.125f : -1e30f;
      }
    }
    float al[4];
#pragma unroll
    for (int r = 0; r < 4; r++) {
      float t0 = fmaxf(fmaxf(s[0][r], s[1][r]), fmaxf(s[2][r], s[3][r]));
#pragma unroll
      for (int m = 1; m < 16; m <<= 1) t0 = fmaxf(t0, __shfl_xor(t0, m));
      float mnew = fmaxf(mrun[r], t0);
      al[r] = __expf(mrun[r] - mnew);
      mrun[r] = mnew;
    }
#pragma unroll
    for (int j = 0; j < 4; j++)
#pragma unroll
      for (int r = 0; r < 4; r++)
        s[j][r] = __expf(s[j][r] - mrun[r]);
#pragma unroll
    for (int r = 0; r < 4; r++) {
      float rs = s[0][r] + s[1][r] + s[2][r] + s[3][r];
#pragma unroll
      for (int m = 1; m < 16; m <<= 1) rs += __shfl_xor(rs, m);
      lrun[r] = lrun[r] * al[r] + rs;
#pragma unroll
      for (int jd = 0; jd < 4; jd++) oacc[jd][r] *= al[r];
    }
#pragma unroll
    for (int j = 0; j < 4; j++)
#pragma unroll
      for (int r = 0; r < 4; r++)
        Ps[w][lg * 4 + r][j * 16 + lr] = f2bf(s[j][r]);
    asm volatile("s_waitcnt lgkmcnt(0)" ::: "memory");
    __builtin_amdgcn_sched_barrier(0);
#pragma unroll
    for (int ks = 0; ks < 2; ks++) {
      bf16x8 pf = *(const bf16x8*)&Ps[w][lr][ks * 32 + lg * 8];
#pragma unroll
      for (int jd = 0; jd < 4; jd++)
        oacc[jd] = __builtin_amdgcn_mfma_f32_16x16x32_bf16(pf, ldV(bb, jd, ks), oacc[jd], 0, 0, 0);
    }
    VMC(0); BAR();
  }
#pragma unroll
  for (int jd = 0; jd < 4; jd++)
#pragma unroll
    for (int r = 0; r < 4; r++) {
      int row = q0 + w * 16 + lg * 4 + r;
      o[obase + (size_t)row * D_ + jd * 16 + lr] = f2bf(oacc[jd][r] / lrun[r]);
    }
}

// ---------------------------------------------------------------- launch --
extern "C" void kernel_launch(void* const* d_in, const int* in_sizes, int n_in,
                              void* d_out, int out_size, void* d_ws, size_t ws_size,
                              hipStream_t stream)
{
  const int*   idx   = (const int*)  d_in[0];
  const float* tok   = (const float*)d_in[1];
  const float* pos   = (const float*)d_in[2];
  const float* ln1w  = (const float*)d_in[3];
  const float* ln1b  = (const float*)d_in[4];
  const float* wq    = (const float*)d_in[5];
  const float* wk    = (const float*)d_in[6];
  const float* wvw   = (const float*)d_in[7];
  const float* wproj = (const float*)d_in[8];
  const float* bproj = (const float*)d_in[9];
  const float* ln2w  = (const float*)d_in[10];
  const float* ln2b  = (const float*)d_in[11];
  const float* w1    = (const float*)d_in[12];
  const float* b1    = (const float*)d_in[13];
  const float* w2    = (const float*)d_in[14];
  const float* b2    = (const float*)d_in[15];
  const float* lnfw  = (const float*)d_in[16];
  const float* lnfb  = (const float*)d_in[17];
  const float* wout  = (const float*)d_in[18];
  const float* bout  = (const float*)d_in[19];

  hipFuncSetAttribute(reinterpret_cast<const void*>(&gemm256<0>),
                      hipFuncAttributeMaxDynamicSharedMemorySize, 131072);
  hipFuncSetAttribute(reinterpret_cast<const void*>(&gemm256<1>),
                      hipFuncAttributeMaxDynamicSharedMemorySize, 131072);
  hipFuncSetAttribute(reinterpret_cast<const void*>(&gemm512<3>),
                      hipFuncAttributeMaxDynamicSharedMemorySize, 98304);

  char* ws = (char*)d_ws;
  size_t off = 0;
  auto alloc = [&](size_t bytes) {
    void* p = ws + off;
    off += (bytes + 255) & ~(size_t)255;
    return p;
  };
  u16* wqkvT  = (u16*)alloc((size_t)L_ * 3 * D_ * D_ * 2);
  u16* wprojT = (u16*)alloc((size_t)L_ * D_ * D_ * 2);
  u16* w1T    = (u16*)alloc((size_t)L_ * D_ * FF_ * 2);
  u16* w2T    = (u16*)alloc((size_t)L_ * D_ * FF_ * 2);
  u16* woutT  = (u16*)alloc((size_t)D_ * V_ * 2);
  float* x    = (float*)alloc((size_t)M_ * D_ * 4);
  u16* hbuf   = (u16*)alloc((size_t)M_ * D_ * 2);
  u16* qkvbuf = (u16*)alloc((size_t)M_ * QP_ * 2);
  u16* vtb    = (u16*)alloc((size_t)B_ * H_ * HD_ * T_ * 2);
  u16* abuf   = (u16*)alloc((size_t)M_ * D_ * 2);
  u16* f1buf  = (u16*)alloc((size_t)M_ * FF_ * 2);

  dim3 tb(32, 8);
  const size_t DD = (size_t)D_ * D_, DF = (size_t)D_ * FF_;
  transpose_convert<<<dim3(D_ / 32, D_ / 32, L_), tb, 0, stream>>>(wq,    wqkvT,          D_,  D_, DD, 3 * DD);
  transpose_convert<<<dim3(D_ / 32, D_ / 32, L_), tb, 0, stream>>>(wk,    wqkvT + DD,     D_,  D_, DD, 3 * DD);
  transpose_convert<<<dim3(D_ / 32, D_ / 32, L_), tb, 0, stream>>>(wvw,   wqkvT + 2 * DD, D_,  D_, DD, 3 * DD);
  transpose_convert<<<dim3(D_ / 32, D_ / 32, L_), tb, 0, stream>>>(wproj, wprojT,         D_,  D_, DD, DD);
  transpose_convert<<<dim3(FF_ / 32, D_ / 32, L_), tb, 0, stream>>>(w1,   w1T,            D_,  FF_, DF, DF);
  transpose_convert<<<dim3(D_ / 32, FF_ / 32, L_), tb, 0, stream>>>(w2,   w2T,            FF_, D_, DF, DF);
  transpose_convert<<<dim3(V_ / 32, D_ / 32, 1),  tb, 0, stream>>>(wout,  woutT,          D_,  V_, 0, 0);

  embed_kernel<<<M_, 256, 0, stream>>>(idx, tok, pos, x);

  for (int l = 0; l < L_; l++) {
    size_t wo = (size_t)l * DD;
    size_t fo = (size_t)l * DF;
    ln_kernel<<<M_, 256, 0, stream>>>(x, ln1w + l * D_, ln1b + l * D_, hbuf);
    gemm256<0><<<dim3(16 * (QP_ / 256)), 512, 131072, stream>>>(
        hbuf, wqkvT + (size_t)l * 3 * DD, nullptr, qkvbuf, QP_, D_);
    vtrans_kernel<<<dim3(T_ / 64, B_ * H_), 256, 0, stream>>>(qkvbuf, vtb);
    attn_kernel<<<dim3(T_ / 128, B_ * H_), 512, 0, stream>>>(qkvbuf, vtb, abuf);
    gemm_bt<2><<<dim3(M_ / 128, D_ / 128), 256, 0, stream>>>(
        abuf, wprojT + wo, bproj + l * D_, x, x, M_, D_, D_);
    ln_kernel<<<M_, 256, 0, stream>>>(x, ln2w + l * D_, ln2b + l * D_, hbuf);
    gemm256<1><<<dim3(16 * (FF_ / 256)), 512, 131072, stream>>>(
        hbuf, w1T + fo, b1 + l * FF_, f1buf, FF_, D_);
    gemm_bt<2><<<dim3(M_ / 128, D_ / 128), 256, 0, stream>>>(
        f1buf, w2T + fo, b2 + l * D_, x, x, M_, D_, FF_);
  }
  ln_kernel<<<M_, 256, 0, stream>>>(x, lnfw, lnfb, hbuf);
  gemm512<3><<<dim3(8 * (V_ / 256)), 1024, 98304, stream>>>(
      hbuf, woutT, bout, d_out, V_, D_);
}

// Round 18
// 1605.192 us; speedup vs baseline: 3.8675x; 3.8675x over previous
//
#include <hip/hip_runtime.h>
#include <hip/hip_bf16.h>

#define V_  32000
#define D_  1024
#define H_  16
#define L_  4
#define T_  1024
#define B_  4
#define HD_ 64
#define FF_ 4096
#define M_  4096
#define QP_ 3072   // fused qkv row pitch

typedef unsigned short u16;
typedef float  f32x4   __attribute__((ext_vector_type(4)));
typedef float  f32x16  __attribute__((ext_vector_type(16)));
typedef __bf16 bf16x8  __attribute__((ext_vector_type(8)));
typedef u16    us8     __attribute__((ext_vector_type(8)));

typedef __attribute__((address_space(1))) void gvoid;
typedef __attribute__((address_space(3))) void lvoid;

__device__ __forceinline__ void glds16(const void* g, void* l) {
  __builtin_amdgcn_global_load_lds((gvoid*)g, (lvoid*)l, 16, 0, 0);
}
__device__ __forceinline__ u16 f2bf(float f) {
  __hip_bfloat16 h = __float2bfloat16(f);
  return reinterpret_cast<u16&>(h);
}

#define BAR() __builtin_amdgcn_s_barrier()
#define VMC(n) asm volatile("s_waitcnt vmcnt(" #n ")" ::: "memory")
#define LGKMC(n) do { asm volatile("s_waitcnt lgkmcnt(" #n ")" ::: "memory"); \
                      __builtin_amdgcn_sched_barrier(0); } while (0)

// ---------------------------------------------------------------- embed ----
__global__ __launch_bounds__(256) void embed_kernel(
    const int* __restrict__ idx, const float* __restrict__ tok,
    const float* __restrict__ pos, float* __restrict__ x)
{
  int bt = blockIdx.x;
  int t  = bt & (T_ - 1);
  int id = idx[bt];
  float4 a = ((const float4*)(tok + (size_t)id * D_))[threadIdx.x];
  float4 p = ((const float4*)(pos + (size_t)t  * D_))[threadIdx.x];
  a.x += p.x; a.y += p.y; a.z += p.z; a.w += p.w;
  ((float4*)(x + (size_t)bt * D_))[threadIdx.x] = a;
}

// ------------------------------------------------------------ layernorm ----
__global__ __launch_bounds__(256) void ln_kernel(
    const float* __restrict__ x, const float* __restrict__ w,
    const float* __restrict__ b, u16* __restrict__ out)
{
  int row = blockIdx.x;
  float4 v = ((const float4*)(x + (size_t)row * D_))[threadIdx.x];
  float s  = v.x + v.y + v.z + v.w;
  float s2 = v.x * v.x + v.y * v.y + v.z * v.z + v.w * v.w;
#pragma unroll
  for (int m = 1; m < 64; m <<= 1) { s += __shfl_xor(s, m); s2 += __shfl_xor(s2, m); }
  __shared__ float ssum[4], ssum2[4];
  int wv = threadIdx.x >> 6;
  if ((threadIdx.x & 63) == 0) { ssum[wv] = s; ssum2[wv] = s2; }
  __syncthreads();
  s  = ssum[0]  + ssum[1]  + ssum[2]  + ssum[3];
  s2 = ssum2[0] + ssum2[1] + ssum2[2] + ssum2[3];
  float mu  = s * (1.f / D_);
  float var = s2 * (1.f / D_) - mu * mu;
  float rs  = rsqrtf(var + 1e-5f);
  float4 wv4 = ((const float4*)w)[threadIdx.x];
  float4 bv4 = ((const float4*)b)[threadIdx.x];
  u16* o = out + (size_t)row * D_ + threadIdx.x * 4;
  o[0] = f2bf((v.x - mu) * rs * wv4.x + bv4.x);
  o[1] = f2bf((v.y - mu) * rs * wv4.y + bv4.y);
  o[2] = f2bf((v.z - mu) * rs * wv4.z + bv4.z);
  o[3] = f2bf((v.w - mu) * rs * wv4.w + bv4.w);
}

// -------------------------------------------- fp32 [R][C] -> bf16 [C][R] ---
__global__ __launch_bounds__(256) void transpose_convert(
    const float* __restrict__ in, u16* __restrict__ out, int R, int C,
    size_t inStride, size_t outStride)
{
  __shared__ float tile[32][33];
  in  += (size_t)blockIdx.z * inStride;
  out += (size_t)blockIdx.z * outStride;
  int c  = blockIdx.x * 32 + threadIdx.x;
  int r0 = blockIdx.y * 32;
#pragma unroll
  for (int j = 0; j < 4; j++)
    tile[threadIdx.y + 8 * j][threadIdx.x] =
        in[(size_t)(r0 + threadIdx.y + 8 * j) * C + c];
  __syncthreads();
  int rr = r0 + threadIdx.x;
  int cb = blockIdx.x * 32;
#pragma unroll
  for (int j = 0; j < 4; j++)
    out[(size_t)(cb + threadIdx.y + 8 * j) * R + rr] =
        f2bf(tile[threadIdx.x][threadIdx.y + 8 * j]);
}

// ------------------------------- V^T materialize: qkv -> vtb[bh][64][T] ----
__global__ __launch_bounds__(256) void vtrans_kernel(
    const u16* __restrict__ qkv, u16* __restrict__ vtb)
{
  __shared__ u16 tile[64][72];
  int tt = blockIdx.x, bh = blockIdx.y;
  int b = bh >> 4, h = bh & 15;
  const u16* src = qkv + ((size_t)(b * T_ + tt * 64)) * QP_ + 2 * D_ + h * HD_;
#pragma unroll
  for (int it = 0; it < 2; it++) {
    int u = it * 256 + threadIdx.x;
    int r = u >> 3, c = (u & 7) << 3;
    *(us8*)&tile[r][c] = *(const us8*)&src[(size_t)r * QP_ + c];
  }
  __syncthreads();
#pragma unroll
  for (int it = 0; it < 2; it++) {
    int u = it * 256 + threadIdx.x;
    int d = u >> 3, t8 = (u & 7) << 3;
    us8 v;
#pragma unroll
    for (int j = 0; j < 8; j++) v[j] = tile[t8 + j][d];
    *(us8*)&vtb[((size_t)bh * HD_ + d) * T_ + tt * 64 + t8] = v;
  }
}

// ---------------------------------------------------- 128x128 GEMM --------
// EPI 0: +bias -> bf16 | 1: +bias,relu -> bf16 | 2: +bias+resid -> f32 | 3: +bias -> f32
template<int EPI>
__global__ __launch_bounds__(256) void gemm_bt(
    const u16* __restrict__ A, const u16* __restrict__ Bt,
    const float* __restrict__ bias, const float* __restrict__ resid,
    void* __restrict__ Cout, int M, int N, int K)
{
  __shared__ u16 As[128 * 32];
  __shared__ u16 Bs[128 * 32];
  const int tid = threadIdx.x;
  const int m0 = blockIdx.x * 128;
  const int n0 = blockIdx.y * 128;
  const int w = tid >> 6, lane = tid & 63, lg = lane >> 4, lr = lane & 15;
  const int wr = w >> 1, wc = w & 1;
  f32x4 acc[4][4] = {};
  const int srow = tid >> 2;
  const int scol = (tid & 3) << 3;
  const u16* ap = A  + (size_t)(m0 + srow) * K + scol;
  const u16* bp = Bt + (size_t)(n0 + srow) * K + scol;
  u16* alds  = &As[tid * 8];
  u16* alds2 = &As[2048 + tid * 8];
  u16* blds  = &Bs[tid * 8];
  u16* blds2 = &Bs[2048 + tid * 8];
  for (int k0 = 0; k0 < K; k0 += 32) {
    __syncthreads();
    glds16(ap + k0,                  alds);
    glds16(ap + (size_t)64 * K + k0, alds2);
    glds16(bp + k0,                  blds);
    glds16(bp + (size_t)64 * K + k0, blds2);
    __syncthreads();
    bf16x8 af[4], bfr[4];
#pragma unroll
    for (int i = 0; i < 4; i++)
      af[i] = *(const bf16x8*)&As[(wr * 64 + i * 16 + lr) * 32 + lg * 8];
#pragma unroll
    for (int j = 0; j < 4; j++)
      bfr[j] = *(const bf16x8*)&Bs[(wc * 64 + j * 16 + lr) * 32 + lg * 8];
#pragma unroll
    for (int i = 0; i < 4; i++)
#pragma unroll
      for (int j = 0; j < 4; j++)
        acc[i][j] = __builtin_amdgcn_mfma_f32_16x16x32_bf16(af[i], bfr[j], acc[i][j], 0, 0, 0);
  }
#pragma unroll
  for (int i = 0; i < 4; i++) {
#pragma unroll
    for (int j = 0; j < 4; j++) {
      int col = n0 + wc * 64 + j * 16 + lr;
      float bv = bias ? bias[col] : 0.f;
#pragma unroll
      for (int r = 0; r < 4; r++) {
        int row = m0 + wr * 64 + i * 16 + lg * 4 + r;
        float val = acc[i][j][r] + bv;
        size_t o = (size_t)row * N + col;
        if (EPI == 0)      ((u16*)Cout)[o]   = f2bf(val);
        else if (EPI == 1) ((u16*)Cout)[o]   = f2bf(val > 0.f ? val : 0.f);
        else if (EPI == 2) ((float*)Cout)[o] = resid[o] + val;
        else               ((float*)Cout)[o] = val;
      }
    }
  }
}

// ---------------------------------------------------- 256x256 GEMM --------
// 32x32x16 MFMA, rotating fragment sets, 1 barrier per K-tile (r7/r10 best).
#define CLUSTER(AF, BV, MS) do { \
  __builtin_amdgcn_s_setprio(1); \
  _Pragma("unroll") for (int mq_ = 0; mq_ < 2; ++mq_) \
  _Pragma("unroll") for (int nq_ = 0; nq_ < 2; ++nq_) \
  _Pragma("unroll") for (int kq_ = 0; kq_ < 2; ++kq_) \
    acc[(MS)+mq_][nq_] = __builtin_amdgcn_mfma_f32_32x32x16_bf16( \
        AF[mq_][kq_], BV[nq_][kq_], acc[(MS)+mq_][nq_], 0, 0, 0); \
  __builtin_amdgcn_s_setprio(0); \
} while (0)

// M fixed = 4096 (16 row-tiles). Grid = 16 * (N/256), flattened 1D.
// EPI 0: +bias -> bf16 | 1: +bias,relu -> bf16 | 3: +bias -> f32 (nt)
template<int EPI>
__global__ __launch_bounds__(512, 2) void gemm256(
    const u16* __restrict__ A, const u16* __restrict__ Bt,
    const float* __restrict__ bias, void* __restrict__ Cout, int N, int K)
{
  extern __shared__ char smem[];
  const int tid = threadIdx.x;
  // bijective XCD swizzle (m204)
  const int nwg = gridDim.x;
  const int orig = blockIdx.x;
  const int qq = nwg >> 3, rr = nwg & 7, xcd = orig & 7, lid = orig >> 3;
  const int swz = (xcd < rr ? xcd * (qq + 1) : rr * (qq + 1) + (xcd - rr) * qq) + lid;
  const int m0 = (swz & 15) << 8;
  const int n0 = (swz >> 4) << 8;
  const int NT = K >> 6;

  const int wid = tid >> 6, lane = tid & 63;
  const int wr = wid >> 2, wc = wid & 3;
  const int l31 = lane & 31, lh = lane >> 5;
  // parity slot swizzle (verified r6: conflicts 2.46e7 -> 0)
  const int gsw = (lane & 7) ^ ((lane >> 3) & 3);
  const int srow = tid >> 3, sslot = tid & 7;
  const int sg = (srow & 7) ^ ((srow >> 3) & 3);
  const int scol = ((sslot ^ sg) << 3);
  const u16* Ag = A  + (size_t)(m0 + srow) * K + scol;
  const u16* Bg = Bt + (size_t)(n0 + srow) * K + scol;
  char* ldst = smem + tid * 16;

  auto stA = [&](int bb, int kt, int h) {
    const u16* g = Ag + (size_t)(h << 7) * K + (kt << 6);
    char* l = ldst + bb * 65536 + h * 16384;
    glds16(g, l);
    glds16(g + ((size_t)K << 6), l + 8192);
  };
  auto stB = [&](int bb, int kt, int h) {
    const u16* g = Bg + (size_t)(h << 7) * K + (kt << 6);
    char* l = ldst + bb * 65536 + 32768 + h * 16384;
    glds16(g, l);
    glds16(g + ((size_t)K << 6), l + 8192);
  };
  auto ldA = [&](int bb, int mf, int ks) {
    return *(const bf16x8*)(smem + bb * 65536 +
        ((wr * 128 + mf * 32 + l31) << 7) + (((ks * 2 + lh) ^ gsw) << 4));
  };
  auto ldB = [&](int bb, int nf, int ks) {
    return *(const bf16x8*)(smem + bb * 65536 + 32768 +
        ((wc * 64 + nf * 32 + l31) << 7) + (((ks * 2 + lh) ^ gsw) << 4));
  };

  f32x16 acc[4][2] = {};
  bf16x8 afA[2][2], afB[2][2], bfvA[2][2], bfvB[2][2];

  // prologue: stage tile0 fully, drain, barrier
  stA(0, 0, 0); stA(0, 0, 1); stB(0, 0, 0); stB(0, 0, 1);
  VMC(0); BAR();

  for (int t = 0; t < NT; ++t) {
    const int bb = t & 1;
    if (t + 1 < NT) {
      stA(bb ^ 1, t + 1, 0); stA(bb ^ 1, t + 1, 1);
      stB(bb ^ 1, t + 1, 0); stB(bb ^ 1, t + 1, 1);
    }
#pragma unroll
    for (int i = 0; i < 2; i++) {
      afA[i][0]  = ldA(bb, i, 0);     afA[i][1]  = ldA(bb, i, 1);
      bfvA[i][0] = ldB(bb, i, 0);     bfvA[i][1] = ldB(bb, i, 1);
    }
#pragma unroll
    for (int i = 0; i < 2; i++) { afB[i][0] = ldA(bb, 2 + i, 0); afB[i][1] = ldA(bb, 2 + i, 1); }
    LGKMC(4);
    CLUSTER(afA, bfvA, 0);
#pragma unroll
    for (int i = 0; i < 2; i++) { bfvB[i][0] = ldB(bb, i, 2); bfvB[i][1] = ldB(bb, i, 3); }
#pragma unroll
    for (int i = 0; i < 2; i++) { afA[i][0] = ldA(bb, i, 2); afA[i][1] = ldA(bb, i, 3); }
    LGKMC(8);
    CLUSTER(afB, bfvA, 2);
#pragma unroll
    for (int i = 0; i < 2; i++) { afB[i][0] = ldA(bb, 2 + i, 2); afB[i][1] = ldA(bb, 2 + i, 3); }
    LGKMC(4);
    CLUSTER(afA, bfvB, 0);
    LGKMC(0);
    CLUSTER(afB, bfvB, 2);
    VMC(0); BAR();
  }

  // C/D layout (m74/m101): col = lane&31, row = (v&3) + 8*(v>>2) + 4*lh
#pragma unroll
  for (int nf = 0; nf < 2; ++nf) {
    const int col = n0 + wc * 64 + nf * 32 + l31;
    const float bv = bias ? bias[col] : 0.f;
#pragma unroll
    for (int mf = 0; mf < 4; ++mf) {
#pragma unroll
      for (int v = 0; v < 16; ++v) {
        const int row = m0 + wr * 128 + mf * 32 + (v & 3) + 8 * (v >> 2) + 4 * lh;
        float val = acc[mf][nf][v] + bv;
        size_t o = (size_t)row * N + col;
        if (EPI == 0)      ((u16*)Cout)[o]   = f2bf(val);
        else if (EPI == 1) ((u16*)Cout)[o]   = f2bf(val > 0.f ? val : 0.f);
        else               __builtin_nontemporal_store(val, (float*)Cout + o);
      }
    }
  }
}

// ---------------------------------------------------- flash attention -----
// reads fused qkv (q,k) + pre-transposed V^T (vtb[bh][64][T]); writes o.
// LPT dispatch: qt reversed so longest blocks (most K-tiles) issue first.
__global__ __launch_bounds__(512) void attn_kernel(
    const u16* __restrict__ qkv, const u16* __restrict__ vtb,
    u16* __restrict__ o)
{
  __shared__ u16 Ks[2][64][64];
  __shared__ u16 Vs[2][64][64];
  __shared__ u16 Ps[8][16][72];
  const int qt = gridDim.x - 1 - blockIdx.x;   // longest-first packing
  const int bh = blockIdx.y;
  const int b = bh >> 4, h = bh & 15;
  const int tid = threadIdx.x;
  const int w = tid >> 6, lane = tid & 63, lg = lane >> 4, lr = lane & 15;
  const int q0 = qt * 128;
  const size_t qbase = ((size_t)b * T_) * QP_ + h * HD_;
  const size_t obase = ((size_t)b * T_) * D_ + h * HD_;
  const u16* qb = qkv + qbase;
  const u16* kb = qkv + qbase + D_;
  const u16* vtbh = vtb + (size_t)bh * HD_ * T_;
  bf16x8 qf[2];
  const int qrow = q0 + w * 16 + lr;
#pragma unroll
  for (int ks = 0; ks < 2; ks++)
    qf[ks] = *(const bf16x8*)&qb[(size_t)qrow * QP_ + ks * 32 + lg * 8];
  f32x4 oacc[4] = {};
  float mrun[4] = {-1e30f, -1e30f, -1e30f, -1e30f};
  float lrun[4] = {0.f, 0.f, 0.f, 0.f};
  const int srow = tid >> 3, sslot = tid & 7;
  const int sg = (srow & 7) ^ ((srow >> 3) & 3);
  const int scol = (sslot ^ sg) << 3;
  u16* kdst = &Ks[0][0][0] + tid * 8;
  u16* vdst = &Vs[0][0][0] + tid * 8;
  auto stage = [&](int kt, int bb) {
    glds16(kb + (size_t)(kt * 64 + srow) * QP_ + scol, kdst + bb * 4096);
    glds16(vtbh + (size_t)srow * T_ + kt * 64 + scol, vdst + bb * 4096);
  };
  auto ldK = [&](int bb, int j, int ks) {
    int r = j * 16 + lr;
    int g = (r & 7) ^ ((r >> 3) & 3);
    return *(const bf16x8*)&Ks[bb][r][((ks * 4 + lg) ^ g) << 3];
  };
  auto ldV = [&](int bb, int jd, int ks) {
    int r = jd * 16 + lr;
    int g = (r & 7) ^ ((r >> 3) & 3);
    return *(const bf16x8*)&Vs[bb][r][((ks * 4 + lg) ^ g) << 3];
  };

  const int ktmax = 2 * qt + 1;
  stage(0, 0);
  VMC(0); BAR();
  for (int kt = 0; kt <= ktmax; kt++) {
    const int bb = kt & 1;
    if (kt < ktmax) stage(kt + 1, bb ^ 1);
    f32x4 s[4] = {};
#pragma unroll
    for (int ks = 0; ks < 2; ks++)
#pragma unroll
      for (int j = 0; j < 4; j++)
        s[j] = __builtin_amdgcn_mfma_f32_16x16x32_bf16(qf[ks], ldK(bb, j, ks), s[j], 0, 0, 0);
#pragma unroll
    for (int j = 0; j < 4; j++) {
      int key = kt * 64 + j * 16 + lr;
#pragma unroll
      for (int r = 0; r < 4; r++) {
        int qr = q0 + w * 16 + lg * 4 + r;
        s[j][r] = (key <= qr) ? s[j][r] * 0.125f : -1e30f;
      }
    }
    float al[4];
#pragma unroll
    for (int r = 0; r < 4; r++) {
      float t0 = fmaxf(fmaxf(s[0][r], s[1][r]), fmaxf(s[2][r], s[3][r]));
#pragma unroll
      for (int m = 1; m < 16; m <<= 1) t0 = fmaxf(t0, __shfl_xor(t0, m));
      float mnew = fmaxf(mrun[r], t0);
      al[r] = __expf(mrun[r] - mnew);
      mrun[r] = mnew;
    }
#pragma unroll
    for (int j = 0; j < 4; j++)
#pragma unroll
      for (int r = 0; r < 4; r++)
        s[j][r] = __expf(s[j][r] - mrun[r]);
#pragma unroll
    for (int r = 0; r < 4; r++) {
      float rs = s[0][r] + s[1][r] + s[2][r] + s[3][r];
#pragma unroll
      for (int m = 1; m < 16; m <<= 1) rs += __shfl_xor(rs, m);
      lrun[r] = lrun[r] * al[r] + rs;
#pragma unroll
      for (int jd = 0; jd < 4; jd++) oacc[jd][r] *= al[r];
    }
#pragma unroll
    for (int j = 0; j < 4; j++)
#pragma unroll
      for (int r = 0; r < 4; r++)
        Ps[w][lg * 4 + r][j * 16 + lr] = f2bf(s[j][r]);
    asm volatile("s_waitcnt lgkmcnt(0)" ::: "memory");
    __builtin_amdgcn_sched_barrier(0);
#pragma unroll
    for (int ks = 0; ks < 2; ks++) {
      bf16x8 pf = *(const bf16x8*)&Ps[w][lr][ks * 32 + lg * 8];
#pragma unroll
      for (int jd = 0; jd < 4; jd++)
        oacc[jd] = __builtin_amdgcn_mfma_f32_16x16x32_bf16(pf, ldV(bb, jd, ks), oacc[jd], 0, 0, 0);
    }
    VMC(0); BAR();
  }
#pragma unroll
  for (int jd = 0; jd < 4; jd++)
#pragma unroll
    for (int r = 0; r < 4; r++) {
      int row = q0 + w * 16 + lg * 4 + r;
      o[obase + (size_t)row * D_ + jd * 16 + lr] = f2bf(oacc[jd][r] / lrun[r]);
    }
}

// ---------------------------------------------------------------- launch --
extern "C" void kernel_launch(void* const* d_in, const int* in_sizes, int n_in,
                              void* d_out, int out_size, void* d_ws, size_t ws_size,
                              hipStream_t stream)
{
  const int*   idx   = (const int*)  d_in[0];
  const float* tok   = (const float*)d_in[1];
  const float* pos   = (const float*)d_in[2];
  const float* ln1w  = (const float*)d_in[3];
  const float* ln1b  = (const float*)d_in[4];
  const float* wq    = (const float*)d_in[5];
  const float* wk    = (const float*)d_in[6];
  const float* wvw   = (const float*)d_in[7];
  const float* wproj = (const float*)d_in[8];
  const float* bproj = (const float*)d_in[9];
  const float* ln2w  = (const float*)d_in[10];
  const float* ln2b  = (const float*)d_in[11];
  const float* w1    = (const float*)d_in[12];
  const float* b1    = (const float*)d_in[13];
  const float* w2    = (const float*)d_in[14];
  const float* b2    = (const float*)d_in[15];
  const float* lnfw  = (const float*)d_in[16];
  const float* lnfb  = (const float*)d_in[17];
  const float* wout  = (const float*)d_in[18];
  const float* bout  = (const float*)d_in[19];

  hipFuncSetAttribute(reinterpret_cast<const void*>(&gemm256<0>),
                      hipFuncAttributeMaxDynamicSharedMemorySize, 131072);
  hipFuncSetAttribute(reinterpret_cast<const void*>(&gemm256<1>),
                      hipFuncAttributeMaxDynamicSharedMemorySize, 131072);
  hipFuncSetAttribute(reinterpret_cast<const void*>(&gemm256<3>),
                      hipFuncAttributeMaxDynamicSharedMemorySize, 131072);

  char* ws = (char*)d_ws;
  size_t off = 0;
  auto alloc = [&](size_t bytes) {
    void* p = ws + off;
    off += (bytes + 255) & ~(size_t)255;
    return p;
  };
  u16* wqkvT  = (u16*)alloc((size_t)L_ * 3 * D_ * D_ * 2);
  u16* wprojT = (u16*)alloc((size_t)L_ * D_ * D_ * 2);
  u16* w1T    = (u16*)alloc((size_t)L_ * D_ * FF_ * 2);
  u16* w2T    = (u16*)alloc((size_t)L_ * D_ * FF_ * 2);
  u16* woutT  = (u16*)alloc((size_t)D_ * V_ * 2);
  float* x    = (float*)alloc((size_t)M_ * D_ * 4);
  u16* hbuf   = (u16*)alloc((size_t)M_ * D_ * 2);
  u16* qkvbuf = (u16*)alloc((size_t)M_ * QP_ * 2);
  u16* vtb    = (u16*)alloc((size_t)B_ * H_ * HD_ * T_ * 2);
  u16* abuf   = (u16*)alloc((size_t)M_ * D_ * 2);
  u16* f1buf  = (u16*)alloc((size_t)M_ * FF_ * 2);

  dim3 tb(32, 8);
  const size_t DD = (size_t)D_ * D_, DF = (size_t)D_ * FF_;
  transpose_convert<<<dim3(D_ / 32, D_ / 32, L_), tb, 0, stream>>>(wq,    wqkvT,          D_,  D_, DD, 3 * DD);
  transpose_convert<<<dim3(D_ / 32, D_ / 32, L_), tb, 0, stream>>>(wk,    wqkvT + DD,     D_,  D_, DD, 3 * DD);
  transpose_convert<<<dim3(D_ / 32, D_ / 32, L_), tb, 0, stream>>>(wvw,   wqkvT + 2 * DD, D_,  D_, DD, 3 * DD);
  transpose_convert<<<dim3(D_ / 32, D_ / 32, L_), tb, 0, stream>>>(wproj, wprojT,         D_,  D_, DD, DD);
  transpose_convert<<<dim3(FF_ / 32, D_ / 32, L_), tb, 0, stream>>>(w1,   w1T,            D_,  FF_, DF, DF);
  transpose_convert<<<dim3(D_ / 32, FF_ / 32, L_), tb, 0, stream>>>(w2,   w2T,            FF_, D_, DF, DF);
  transpose_convert<<<dim3(V_ / 32, D_ / 32, 1),  tb, 0, stream>>>(wout,  woutT,          D_,  V_, 0, 0);

  embed_kernel<<<M_, 256, 0, stream>>>(idx, tok, pos, x);

  for (int l = 0; l < L_; l++) {
    size_t wo = (size_t)l * DD;
    size_t fo = (size_t)l * DF;
    ln_kernel<<<M_, 256, 0, stream>>>(x, ln1w + l * D_, ln1b + l * D_, hbuf);
    gemm256<0><<<dim3(16 * (QP_ / 256)), 512, 131072, stream>>>(
        hbuf, wqkvT + (size_t)l * 3 * DD, nullptr, qkvbuf, QP_, D_);
    vtrans_kernel<<<dim3(T_ / 64, B_ * H_), 256, 0, stream>>>(qkvbuf, vtb);
    attn_kernel<<<dim3(T_ / 128, B_ * H_), 512, 0, stream>>>(qkvbuf, vtb, abuf);
    gemm_bt<2><<<dim3(M_ / 128, D_ / 128), 256, 0, stream>>>(
        abuf, wprojT + wo, bproj + l * D_, x, x, M_, D_, D_);
    ln_kernel<<<M_, 256, 0, stream>>>(x, ln2w + l * D_, ln2b + l * D_, hbuf);
    gemm256<1><<<dim3(16 * (FF_ / 256)), 512, 131072, stream>>>(
        hbuf, w1T + fo, b1 + l * FF_, f1buf, FF_, D_);
    gemm_bt<2><<<dim3(M_ / 128, D_ / 128), 256, 0, stream>>>(
        f1buf, w2T + fo, b2 + l * D_, x, x, M_, D_, FF_);
  }
  ln_kernel<<<M_, 256, 0, stream>>>(x, lnfw, lnfb, hbuf);
  gemm256<3><<<dim3(16 * (V_ / 256)), 512, 131072, stream>>>(
      hbuf, woutT, bout, d_out, V_, D_);
}